// Round 7
// baseline (516.739 us; speedup 1.0000x reference)
//
#include <hip/hip_runtime.h>
#include <math.h>

typedef __attribute__((ext_vector_type(8))) short short8;
typedef __attribute__((ext_vector_type(4))) float f32x4;
typedef unsigned short u16;
typedef unsigned int u32;

#define HW   96
#define LPIX 9216
static constexpr float kScale = 0.17677669529663687f;  // 1/sqrt(32)

__device__ inline u16 f2bf(float f) {
    u32 x = __float_as_uint(f);
    return (u16)((x + 0x7fffu + ((x >> 16) & 1u)) >> 16);   // RNE
}
__device__ inline float bf2f(u16 v) { return __uint_as_float((u32)v << 16); }

// ---------------------------------------------------------------------------
// NCHW fp32 -> NHWC bf16 transpose-cast. grid (96 y, 8 b), block 256.
// ---------------------------------------------------------------------------
template <int C>
__global__ __launch_bounds__(256) void cast_nchw_nhwc(
    const float* __restrict__ in, u16* __restrict__ out)
{
    const int y = blockIdx.x, b = blockIdx.y, tid = threadIdx.x;
    __shared__ float sT[HW * C];
    for (int i = tid; i < HW * C; i += 256) {
        int c = i / HW, xx = i - c * HW;
        sT[xx * C + c] = in[(((size_t)b * C + c) * HW + y) * HW + xx];
    }
    __syncthreads();
    for (int i = tid; i < HW * (C / 8); i += 256) {
        int c8 = i % (C / 8), xx = i / (C / 8);
        union { short8 v8; u16 u[8]; } pk;
#pragma unroll
        for (int j = 0; j < 8; ++j) pk.u[j] = f2bf(sT[xx * C + c8 * 8 + j]);
        *(short8*)&out[(((size_t)b * HW + y) * HW + xx) * C + c8 * 8] = pk.v8;
    }
}

// ---------------------------------------------------------------------------
// conv weights [co 128][ci CIN][3][3] fp32 -> [f 9][ci/32][co 128][32] bf16
// ---------------------------------------------------------------------------
__global__ void cast_conv_w(const float* __restrict__ w, u16* __restrict__ wp, int CIN)
{
    int n = 9 * CIN * 128;
    int i = blockIdx.x * 256 + threadIdx.x;
    if (i >= n) return;
    int cil = i & 31; int t = i >> 5; int co = t & 127; int t2 = t >> 7;
    int nc5 = CIN >> 5;
    int c5 = t2 % nc5; int f = t2 / nc5;
    int ci = c5 * 32 + cil;
    wp[i] = f2bf(w[(size_t)(co * CIN + ci) * 9 + f]);
}

// dense matrix fp32 -> bf16 (same layout)
__global__ void cast_mat(const float* __restrict__ in, u16* __restrict__ out, int n)
{
    int i = blockIdx.x * 256 + threadIdx.x;
    if (i < n) out[i] = f2bf(in[i]);
}

// ---------------------------------------------------------------------------
// conv3x3 + BN + ReLU as flat GEMM over pixels (implicit im2col).
// M=128 co x N=128 flat pixels per block; K-loop = 9 taps x 64-ci chunks.
// grid (72 px-blocks, 8 b), block 256 (2x2 waves, each M=64 x N=64).
// ---------------------------------------------------------------------------
template <int CIN, bool OUT_F32>
__global__ __launch_bounds__(256, 3) void conv_gemm(
    const u16* __restrict__ in, const u16* __restrict__ wp,
    const float* __restrict__ g, const float* __restrict__ be, void* outv)
{
    constexpr int NC6 = CIN / 64;       // 64-ci chunks
    constexpr int NC5 = CIN / 32;
    const int l0 = blockIdx.x * 128;
    const int b  = blockIdx.y;
    const int tid = threadIdx.x, lane = tid & 63, wv = tid >> 6;
    const int wm = wv >> 1, wn = wv & 1;
    const int lx = lane & 15, q = lane >> 4;

    __shared__ char smem[36864];
    u16* sA = (u16*)smem;               // [co 128][ci 64 pitch 72]
    u16* sB = sA + 128 * 72;            // [px 128][ci 64 pitch 72]
    float* sT = (float*)smem;           // epilogue [px 128][co 64 pitch 65]

    f32x4 acc[4][4];                    // [mt co][nt px]
#pragma unroll
    for (int mt = 0; mt < 4; ++mt)
#pragma unroll
        for (int nt = 0; nt < 4; ++nt) acc[mt][nt] = (f32x4){0.f, 0.f, 0.f, 0.f};

    for (int c6 = 0; c6 < NC6; ++c6) {
        for (int f = 0; f < 9; ++f) {
            const int dy = f / 3 - 1, dx = f % 3 - 1;
            __syncthreads();
            // stage A (weights): 1024 short8, coalesced from wp
            for (int i = tid; i < 1024; i += 256) {
                int ci8 = i & 7, co = i >> 3;
                int c5 = c6 * 2 + (ci8 >> 2);
                short8 v = *(const short8*)&wp[(size_t)(((f * NC5 + c5) * 128 + co) * 32
                                                         + (ci8 & 3) * 8)];
                *(short8*)&sA[co * 72 + ci8 * 8] = v;
            }
            // stage B (shifted input pixels): 64-ci chunk, 8 short8 x 128 px
            for (int i = tid; i < 1024; i += 256) {
                int ci8 = i & 7, p = i >> 3;
                int l = l0 + p;
                int y = l / 96, x = l - y * 96;
                int yy = y + dy, xx = x + dx;
                short8 v = {0, 0, 0, 0, 0, 0, 0, 0};
                if (yy >= 0 && yy < HW && xx >= 0 && xx < HW)
                    v = *(const short8*)&in[(((size_t)b * HW + yy) * HW + xx) * CIN
                                            + c6 * 64 + ci8 * 8];
                *(short8*)&sB[p * 72 + ci8 * 8] = v;
            }
            __syncthreads();
#pragma unroll
            for (int kk = 0; kk < 2; ++kk) {
                short8 af[4], bfr[4];
#pragma unroll
                for (int mt = 0; mt < 4; ++mt)
                    af[mt] = *(const short8*)&sA[(wm * 64 + mt * 16 + lx) * 72 + kk * 32 + q * 8];
#pragma unroll
                for (int nt = 0; nt < 4; ++nt)
                    bfr[nt] = *(const short8*)&sB[(wn * 64 + nt * 16 + lx) * 72 + kk * 32 + q * 8];
#pragma unroll
                for (int mt = 0; mt < 4; ++mt)
#pragma unroll
                    for (int nt = 0; nt < 4; ++nt)
                        acc[mt][nt] = __builtin_amdgcn_mfma_f32_16x16x32_bf16(
                            af[mt], bfr[nt], acc[mt][nt], 0, 0, 0);
            }
        }
    }

    const float rs = rsqrtf(1.f + 1e-5f);
    if (OUT_F32) {
        float* out = (float*)outv;
#pragma unroll
        for (int mt = 0; mt < 4; ++mt) {
#pragma unroll
            for (int reg = 0; reg < 4; ++reg) {
                int co = wm * 64 + mt * 16 + q * 4 + reg;
                float sc = g[co] * rs, bb = be[co];
#pragma unroll
                for (int nt = 0; nt < 4; ++nt) {
                    int l = l0 + wn * 64 + nt * 16 + lx;
                    out[((size_t)b * 128 + co) * LPIX + l] =
                        fmaxf(fmaf(acc[mt][nt][reg], sc, bb), 0.f);
                }
            }
        }
    } else {
        u16* out = (u16*)outv;
        for (int mh = 0; mh < 2; ++mh) {
            __syncthreads();
            if (wm == mh) {
#pragma unroll
                for (int mt = 0; mt < 4; ++mt)
#pragma unroll
                    for (int nt = 0; nt < 4; ++nt)
#pragma unroll
                        for (int reg = 0; reg < 4; ++reg)
                            sT[(wn * 64 + nt * 16 + lx) * 65 + mt * 16 + q * 4 + reg] =
                                acc[mt][nt][reg];
            }
            __syncthreads();
            for (int i = tid; i < 1024; i += 256) {
                int cog = i & 7, px = i >> 3;
                union { short8 v8; u16 u[8]; } pk;
#pragma unroll
                for (int j = 0; j < 8; ++j) {
                    int co = mh * 64 + cog * 8 + j;
                    pk.u[j] = f2bf(fmaxf(fmaf(sT[px * 65 + cog * 8 + j], g[co] * rs, be[co]), 0.f));
                }
                *(short8*)&out[((size_t)b * LPIX + l0 + px) * 128 + mh * 64 + cog * 8] = pk.v8;
            }
        }
    }
}

// ---------------------------------------------------------------------------
// 128->128 linear + bias via MFMA. in/out NHWC-flat bf16 [b*L][128].
// grid 1152 (64 px per block), block 256 (2x2 waves: M=64 x N=32).
// ---------------------------------------------------------------------------
__global__ __launch_bounds__(256) void linear_mfma(
    const u16* __restrict__ in, const u16* __restrict__ wp,
    const float* __restrict__ bias, u16* __restrict__ out)
{
    const int l0 = blockIdx.x * 64;
    const int tid = threadIdx.x, lane = tid & 63, wv = tid >> 6;
    const int wm = wv >> 1, wn = wv & 1;
    const int lx = lane & 15, q = lane >> 4;

    __shared__ char smem[4 * 64 * 40 * 2 + 4 * 128 * 40 * 2];   // 61,440 B
    u16* sX = (u16*)smem;                        // [c4][px 64][32 pitch 40]
    u16* sW = (u16*)(smem + 4 * 64 * 40 * 2);    // [c4][co 128][32 pitch 40]
    float* sT = (float*)smem;                    // epilogue [64][65]

    for (int i = tid; i < 1024; i += 256) {
        int k8 = i & 15, px = i >> 4;
        short8 v = *(const short8*)&in[((size_t)(l0 + px)) * 128 + k8 * 8];
        *(short8*)&sX[((k8 >> 2) * 64 + px) * 40 + (k8 & 3) * 8] = v;
    }
    for (int i = tid; i < 2048; i += 256) {
        int k8 = i & 15, co = i >> 4;
        short8 v = *(const short8*)&wp[(size_t)co * 128 + k8 * 8];
        *(short8*)&sW[((k8 >> 2) * 128 + co) * 40 + (k8 & 3) * 8] = v;
    }
    __syncthreads();

    f32x4 acc[4][2];
#pragma unroll
    for (int mt = 0; mt < 4; ++mt)
#pragma unroll
        for (int nt = 0; nt < 2; ++nt) acc[mt][nt] = (f32x4){0.f, 0.f, 0.f, 0.f};

#pragma unroll
    for (int c4 = 0; c4 < 4; ++c4) {
        short8 af[4], bfr[2];
#pragma unroll
        for (int mt = 0; mt < 4; ++mt)
            af[mt] = *(const short8*)&sW[(c4 * 128 + wm * 64 + mt * 16 + lx) * 40 + q * 8];
#pragma unroll
        for (int nt = 0; nt < 2; ++nt)
            bfr[nt] = *(const short8*)&sX[(c4 * 64 + wn * 32 + nt * 16 + lx) * 40 + q * 8];
#pragma unroll
        for (int mt = 0; mt < 4; ++mt)
#pragma unroll
            for (int nt = 0; nt < 2; ++nt)
                acc[mt][nt] = __builtin_amdgcn_mfma_f32_16x16x32_bf16(
                    af[mt], bfr[nt], acc[mt][nt], 0, 0, 0);
    }

    for (int mh = 0; mh < 2; ++mh) {
        __syncthreads();
        if (wm == mh) {
#pragma unroll
            for (int mt = 0; mt < 4; ++mt)
#pragma unroll
                for (int nt = 0; nt < 2; ++nt)
#pragma unroll
                    for (int reg = 0; reg < 4; ++reg)
                        sT[(wn * 32 + nt * 16 + lx) * 65 + mt * 16 + q * 4 + reg] =
                            acc[mt][nt][reg];
        }
        __syncthreads();
        for (int i = tid; i < 512; i += 256) {
            int cog = i & 7, px = i >> 3;
            union { short8 v8; u16 u[8]; } pk;
#pragma unroll
            for (int j = 0; j < 8; ++j) {
                int co = mh * 64 + cog * 8 + j;
                pk.u[j] = f2bf(sT[px * 65 + cog * 8 + j] + bias[co]);
            }
            *(short8*)&out[((size_t)(l0 + px)) * 128 + mh * 64 + cog * 8] = pk.v8;
        }
    }
}

// ---------------------------------------------------------------------------
// attn logits GEMM (MFMA) + bias + scale + softmax over q(9).
// grid (144 l-tiles of 64 px, 4 h, 8 b), block 256 (4 waves).
// ---------------------------------------------------------------------------
__global__ __launch_bounds__(256) void attn_mfma(
    const u16* __restrict__ fgb, const u16* __restrict__ awb,
    const float* __restrict__ ab, u16* __restrict__ A)
{
    const int lt = blockIdx.x, h = blockIdx.y, b = blockIdx.z;
    const int l0 = lt * 64;
    const int tid = threadIdx.x, lane = tid & 63, wv = tid >> 6;
    const int lx = lane & 15, q = lane >> 4;

    __shared__ char smem[4 * 64 * 40 * 2 + 4 * 96 * 40 * 2];   // 51,200 B
    u16* sX = (u16*)smem;                        // [c4][px 64][32 pitch 40]
    u16* sW = (u16*)(smem + 4 * 64 * 40 * 2);    // [c4][row 96][32 pitch 40]
    float* sL = (float*)smem;                    // epilogue logits [px 64][pitch 97]

    for (int i = tid; i < 1024; i += 256) {
        int k8 = i & 15, px = i >> 4;
        short8 v = *(const short8*)&fgb[((size_t)b * LPIX + l0 + px) * 128 + k8 * 8];
        *(short8*)&sX[((k8 >> 2) * 64 + px) * 40 + (k8 & 3) * 8] = v;
    }
    for (int i = tid; i < 1536; i += 256) {
        int k8 = i & 15, rr = i >> 4;           // rr 0..95, rows 81..95 zero-pad
        short8 v = {0, 0, 0, 0, 0, 0, 0, 0};
        if (rr < 81)
            v = *(const short8*)&awb[(size_t)(h * 81 + rr) * 128 + k8 * 8];
        *(short8*)&sW[((k8 >> 2) * 96 + rr) * 40 + (k8 & 3) * 8] = v;
    }
    __syncthreads();

    f32x4 acc[6];
#pragma unroll
    for (int j = 0; j < 6; ++j) acc[j] = (f32x4){0.f, 0.f, 0.f, 0.f};

#pragma unroll
    for (int c4 = 0; c4 < 4; ++c4) {
        short8 af = *(const short8*)&sX[(c4 * 64 + wv * 16 + lx) * 40 + q * 8];
#pragma unroll
        for (int j = 0; j < 6; ++j) {
            short8 bfr = *(const short8*)&sW[(c4 * 96 + j * 16 + lx) * 40 + q * 8];
            acc[j] = __builtin_amdgcn_mfma_f32_16x16x32_bf16(af, bfr, acc[j], 0, 0, 0);
        }
    }

    __syncthreads();   // done reading sX/sW; reuse as sL
#pragma unroll
    for (int j = 0; j < 6; ++j)
#pragma unroll
        for (int reg = 0; reg < 4; ++reg)
            sL[(wv * 16 + q * 4 + reg) * 97 + j * 16 + lx] = acc[j][reg];
    __syncthreads();

    for (int t = tid; t < 576; t += 256) {
        int px = t & 63, p = t >> 6;
        const int rbase = h * 81 + p * 9;
        float lg[9], m = -1e30f;
#pragma unroll
        for (int qq = 0; qq < 9; ++qq) {
            lg[qq] = (sL[px * 97 + p * 9 + qq] + ab[rbase + qq]) * kScale;
            m = fmaxf(m, lg[qq]);
        }
        float s = 0.f;
#pragma unroll
        for (int qq = 0; qq < 9; ++qq) { lg[qq] = __expf(lg[qq] - m); s += lg[qq]; }
        float inv = 1.f / s;
        u16* Ab = &A[(((size_t)(b * 4 + h) * 9 + p) * 9) * LPIX + l0 + px];
#pragma unroll
        for (int qq = 0; qq < 9; ++qq) Ab[(size_t)qq * LPIX] = f2bf(lg[qq] * inv);
    }
}

// ---------------------------------------------------------------------------
// fused einsum + fold (5x5 stencil collapse), LDS-free / fully-coalesced A.
// Block 256 = 4 waves = 4 heads x 64 CONSECUTIVE flat pixels: for every
// (tap,q) the wave reads A at l+const -> 128B coalesced lines (A read once).
// v read directly (bf16, L2-served); S[25]+acc[32] in registers.
// grid (144 l-tiles, 8 b).
// ---------------------------------------------------------------------------
__global__ __launch_bounds__(256) void attn_fold(
    const u16* __restrict__ A, const u16* __restrict__ v,
    u16* __restrict__ out)
{
    const int b    = blockIdx.y;
    const int lane = threadIdx.x & 63;
    const int h    = threadIdx.x >> 6;          // wave index = head
    const int l    = blockIdx.x * 64 + lane;
    const int y    = l / 96, x = l - y * 96;

    // ---- stencil S[5][5] from 9 taps x 9 q of A (coalesced bf16 reads) ----
    float S[25];
#pragma unroll
    for (int i = 0; i < 25; ++i) S[i] = 0.f;

    const u16* Ab = A + ((size_t)(b * 4 + h) * 81) * (size_t)LPIX;
#pragma unroll
    for (int ki = 0; ki < 3; ++ki) {
        const int ly = y + 1 - ki;
        const bool vy = ((unsigned)ly < 96u);
#pragma unroll
        for (int kj = 0; kj < 3; ++kj) {
            const int lx2 = x + 1 - kj;
            if (vy && (unsigned)lx2 < 96u) {
                const u16* Ap = Ab + (size_t)(ki * 3 + kj) * 9 * (size_t)LPIX
                              + (ly * 96 + lx2);
#pragma unroll
                for (int qq = 0; qq < 9; ++qq) {
                    const int qi = qq / 3, qj = qq - qi * 3;
                    S[(qi - ki + 2) * 5 + (qj - kj + 2)] += bf2f(Ap[(size_t)qq * LPIX]);
                }
            }
        }
    }

    // ---- 5x5 stencil over v (this head's 32 channels), direct global ----
    float acc[32];
#pragma unroll
    for (int c = 0; c < 32; ++c) acc[c] = 0.f;

    const u16* vbase = v + (size_t)b * LPIX * 128 + h * 32;
#pragma unroll
    for (int oy = 0; oy < 5; ++oy) {
        const int yy = y + oy - 2;
        if ((unsigned)yy >= 96u) continue;
#pragma unroll
        for (int ox = 0; ox < 5; ++ox) {
            const int xx = x + ox - 2;
            if ((unsigned)xx >= 96u) continue;
            const float sc = S[oy * 5 + ox];
            const u16* vp = vbase + (size_t)(yy * 96 + xx) * 128;
#pragma unroll
            for (int c8 = 0; c8 < 4; ++c8) {
                const uint4 uu = *(const uint4*)&vp[c8 * 8];
                acc[c8 * 8 + 0] = fmaf(sc, __uint_as_float(uu.x << 16),          acc[c8 * 8 + 0]);
                acc[c8 * 8 + 1] = fmaf(sc, __uint_as_float(uu.x & 0xffff0000u), acc[c8 * 8 + 1]);
                acc[c8 * 8 + 2] = fmaf(sc, __uint_as_float(uu.y << 16),          acc[c8 * 8 + 2]);
                acc[c8 * 8 + 3] = fmaf(sc, __uint_as_float(uu.y & 0xffff0000u), acc[c8 * 8 + 3]);
                acc[c8 * 8 + 4] = fmaf(sc, __uint_as_float(uu.z << 16),          acc[c8 * 8 + 4]);
                acc[c8 * 8 + 5] = fmaf(sc, __uint_as_float(uu.z & 0xffff0000u), acc[c8 * 8 + 5]);
                acc[c8 * 8 + 6] = fmaf(sc, __uint_as_float(uu.w << 16),          acc[c8 * 8 + 6]);
                acc[c8 * 8 + 7] = fmaf(sc, __uint_as_float(uu.w & 0xffff0000u), acc[c8 * 8 + 7]);
            }
        }
    }

    u16* ob = &out[((size_t)b * LPIX + l) * 128 + h * 32];
#pragma unroll
    for (int gidx = 0; gidx < 4; ++gidx) {
        union { short8 v8; u16 u[8]; } pk;
#pragma unroll
        for (int j = 0; j < 8; ++j) pk.u[j] = f2bf(acc[gidx * 8 + j]);
        *(short8*)&ob[gidx * 8] = pk.v8;
    }
}

// ---------------------------------------------------------------------------
extern "C" void kernel_launch(void* const* d_in, const int* in_sizes, int n_in,
                              void* d_out, int out_size, void* d_ws, size_t ws_size,
                              hipStream_t stream)
{
    const float* x    = (const float*)d_in[0];
    const float* fg   = (const float*)d_in[1];
    const float* c1w  = (const float*)d_in[2];
    const float* bn1g = (const float*)d_in[3];
    const float* bn1b = (const float*)d_in[4];
    const float* c2w  = (const float*)d_in[5];
    const float* bn2g = (const float*)d_in[6];
    const float* bn2b = (const float*)d_in[7];
    const float* vw   = (const float*)d_in[8];
    const float* vb   = (const float*)d_in[9];
    const float* aw   = (const float*)d_in[10];
    const float* abv  = (const float*)d_in[11];
    const float* pw   = (const float*)d_in[12];
    const float* pb   = (const float*)d_in[13];
    const float* c3w  = (const float*)d_in[14];
    const float* bn3g = (const float*)d_in[15];
    const float* bn3b = (const float*)d_in[16];
    const float* c4w  = (const float*)d_in[17];
    const float* bn4g = (const float*)d_in[18];
    const float* bn4b = (const float*)d_in[19];

    char* wsp = (char*)d_ws;
    size_t off = 0;
    auto carve = [&](size_t bytes) {
        void* pp = wsp + off;
        off += (bytes + 255) & ~(size_t)255;
        return pp;
    };
    u16*   xb   = (u16*)carve((size_t)8 * LPIX * 64 * 2);     // x NHWC bf16
    u16*   fgb  = (u16*)carve((size_t)8 * LPIX * 128 * 2);    // fg NHWC bf16
    u16*   actA = (u16*)carve((size_t)8 * LPIX * 128 * 2);
    u16*   actB = (u16*)carve((size_t)8 * LPIX * 128 * 2);
    u16*   Abuf = (u16*)carve((size_t)8 * 324 * LPIX * 2);    // A bf16
    u16*   w1p  = (u16*)carve((size_t)9 * 2 * 128 * 32 * 2);
    u16*   w2p  = (u16*)carve((size_t)9 * 4 * 128 * 32 * 2);
    u16*   w3p  = (u16*)carve((size_t)9 * 4 * 128 * 32 * 2);
    u16*   w4p  = (u16*)carve((size_t)9 * 4 * 128 * 32 * 2);
    u16*   vwp  = (u16*)carve((size_t)128 * 128 * 2);
    u16*   pwp  = (u16*)carve((size_t)128 * 128 * 2);
    u16*   awb  = (u16*)carve((size_t)324 * 128 * 2);

    // --- pre-casts ---
    cast_nchw_nhwc<64><<<dim3(HW, 8), 256, 0, stream>>>(x, xb);
    cast_nchw_nhwc<128><<<dim3(HW, 8), 256, 0, stream>>>(fg, fgb);
    cast_conv_w<<<(9 * 64 * 128 + 255) / 256, 256, 0, stream>>>(c1w, w1p, 64);
    cast_conv_w<<<(9 * 128 * 128 + 255) / 256, 256, 0, stream>>>(c2w, w2p, 128);
    cast_conv_w<<<(9 * 128 * 128 + 255) / 256, 256, 0, stream>>>(c3w, w3p, 128);
    cast_conv_w<<<(9 * 128 * 128 + 255) / 256, 256, 0, stream>>>(c4w, w4p, 128);
    cast_mat<<<(16384 + 255) / 256, 256, 0, stream>>>(vw, vwp, 16384);
    cast_mat<<<(16384 + 255) / 256, 256, 0, stream>>>(pw, pwp, 16384);
    cast_mat<<<(324 * 128 + 255) / 256, 256, 0, stream>>>(aw, awb, 324 * 128);

    // --- pipeline ---
    conv_gemm<64, false><<<dim3(72, 8), 256, 0, stream>>>(xb, w1p, bn1g, bn1b, actA);
    conv_gemm<128, false><<<dim3(72, 8), 256, 0, stream>>>(actA, w2p, bn2g, bn2b, actB);
    linear_mfma<<<1152, 256, 0, stream>>>(actB, vwp, vb, actA);                 // v
    attn_mfma<<<dim3(144, 4, 8), 256, 0, stream>>>(fgb, awb, abv, Abuf);
    attn_fold<<<dim3(144, 8), 256, 0, stream>>>(Abuf, actA, actB);              // folded
    linear_mfma<<<1152, 256, 0, stream>>>(actB, pwp, pb, actA);                 // p
    conv_gemm<128, false><<<dim3(72, 8), 256, 0, stream>>>(actA, w3p, bn3g, bn3b, actB);
    conv_gemm<128, true><<<dim3(72, 8), 256, 0, stream>>>(actB, w4p, bn4g, bn4b, d_out);
}

// Round 8
// 468.345 us; speedup vs baseline: 1.1033x; 1.1033x over previous
//
#include <hip/hip_runtime.h>
#include <math.h>

typedef __attribute__((ext_vector_type(8))) short short8;
typedef __attribute__((ext_vector_type(4))) float f32x4;
typedef unsigned short u16;
typedef unsigned int u32;

#define HW   96
#define LPIX 9216
static constexpr float kScale = 0.17677669529663687f;  // 1/sqrt(32)

__device__ inline u16 f2bf(float f) {
    u32 x = __float_as_uint(f);
    return (u16)((x + 0x7fffu + ((x >> 16) & 1u)) >> 16);   // RNE
}
__device__ inline float bf2f(u16 v) { return __uint_as_float((u32)v << 16); }

// ---------------------------------------------------------------------------
// NCHW fp32 -> NHWC bf16 transpose-cast. grid (96 y, 8 b), block 256.
// ---------------------------------------------------------------------------
template <int C>
__global__ __launch_bounds__(256) void cast_nchw_nhwc(
    const float* __restrict__ in, u16* __restrict__ out)
{
    const int y = blockIdx.x, b = blockIdx.y, tid = threadIdx.x;
    __shared__ float sT[HW * C];
    for (int i = tid; i < HW * C; i += 256) {
        int c = i / HW, xx = i - c * HW;
        sT[xx * C + c] = in[(((size_t)b * C + c) * HW + y) * HW + xx];
    }
    __syncthreads();
    for (int i = tid; i < HW * (C / 8); i += 256) {
        int c8 = i % (C / 8), xx = i / (C / 8);
        union { short8 v8; u16 u[8]; } pk;
#pragma unroll
        for (int j = 0; j < 8; ++j) pk.u[j] = f2bf(sT[xx * C + c8 * 8 + j]);
        *(short8*)&out[(((size_t)b * HW + y) * HW + xx) * C + c8 * 8] = pk.v8;
    }
}

// ---------------------------------------------------------------------------
// conv weights [co 128][ci CIN][3][3] fp32 -> [f 9][ci/32][co 128][32] bf16
// ---------------------------------------------------------------------------
__global__ void cast_conv_w(const float* __restrict__ w, u16* __restrict__ wp, int CIN)
{
    int n = 9 * CIN * 128;
    int i = blockIdx.x * 256 + threadIdx.x;
    if (i >= n) return;
    int cil = i & 31; int t = i >> 5; int co = t & 127; int t2 = t >> 7;
    int nc5 = CIN >> 5;
    int c5 = t2 % nc5; int f = t2 / nc5;
    int ci = c5 * 32 + cil;
    wp[i] = f2bf(w[(size_t)(co * CIN + ci) * 9 + f]);
}

// dense matrix fp32 -> bf16 (same layout)
__global__ void cast_mat(const float* __restrict__ in, u16* __restrict__ out, int n)
{
    int i = blockIdx.x * 256 + threadIdx.x;
    if (i < n) out[i] = f2bf(in[i]);
}

// ---------------------------------------------------------------------------
// conv3x3 + BN + ReLU as flat GEMM over pixels (implicit im2col).
// M=128 co x N=128 flat pixels per block; K-loop = 9 taps x 64-ci chunks.
// grid (72 px-blocks, 8 b), block 256 (2x2 waves, each M=64 x N=64).
// ---------------------------------------------------------------------------
template <int CIN, bool OUT_F32>
__global__ __launch_bounds__(256, 3) void conv_gemm(
    const u16* __restrict__ in, const u16* __restrict__ wp,
    const float* __restrict__ g, const float* __restrict__ be, void* outv)
{
    constexpr int NC6 = CIN / 64;       // 64-ci chunks
    constexpr int NC5 = CIN / 32;
    const int l0 = blockIdx.x * 128;
    const int b  = blockIdx.y;
    const int tid = threadIdx.x, lane = tid & 63, wv = tid >> 6;
    const int wm = wv >> 1, wn = wv & 1;
    const int lx = lane & 15, q = lane >> 4;

    __shared__ char smem[36864];
    u16* sA = (u16*)smem;               // [co 128][ci 64 pitch 72]
    u16* sB = sA + 128 * 72;            // [px 128][ci 64 pitch 72]
    float* sT = (float*)smem;           // epilogue [px 128][co 64 pitch 65]

    f32x4 acc[4][4];                    // [mt co][nt px]
#pragma unroll
    for (int mt = 0; mt < 4; ++mt)
#pragma unroll
        for (int nt = 0; nt < 4; ++nt) acc[mt][nt] = (f32x4){0.f, 0.f, 0.f, 0.f};

    for (int c6 = 0; c6 < NC6; ++c6) {
        for (int f = 0; f < 9; ++f) {
            const int dy = f / 3 - 1, dx = f % 3 - 1;
            __syncthreads();
            // stage A (weights): 1024 short8, coalesced from wp
            for (int i = tid; i < 1024; i += 256) {
                int ci8 = i & 7, co = i >> 3;
                int c5 = c6 * 2 + (ci8 >> 2);
                short8 v = *(const short8*)&wp[(size_t)(((f * NC5 + c5) * 128 + co) * 32
                                                         + (ci8 & 3) * 8)];
                *(short8*)&sA[co * 72 + ci8 * 8] = v;
            }
            // stage B (shifted input pixels): 64-ci chunk, 8 short8 x 128 px
            for (int i = tid; i < 1024; i += 256) {
                int ci8 = i & 7, p = i >> 3;
                int l = l0 + p;
                int y = l / 96, x = l - y * 96;
                int yy = y + dy, xx = x + dx;
                short8 v = {0, 0, 0, 0, 0, 0, 0, 0};
                if (yy >= 0 && yy < HW && xx >= 0 && xx < HW)
                    v = *(const short8*)&in[(((size_t)b * HW + yy) * HW + xx) * CIN
                                            + c6 * 64 + ci8 * 8];
                *(short8*)&sB[p * 72 + ci8 * 8] = v;
            }
            __syncthreads();
#pragma unroll
            for (int kk = 0; kk < 2; ++kk) {
                short8 af[4], bfr[4];
#pragma unroll
                for (int mt = 0; mt < 4; ++mt)
                    af[mt] = *(const short8*)&sA[(wm * 64 + mt * 16 + lx) * 72 + kk * 32 + q * 8];
#pragma unroll
                for (int nt = 0; nt < 4; ++nt)
                    bfr[nt] = *(const short8*)&sB[(wn * 64 + nt * 16 + lx) * 72 + kk * 32 + q * 8];
#pragma unroll
                for (int mt = 0; mt < 4; ++mt)
#pragma unroll
                    for (int nt = 0; nt < 4; ++nt)
                        acc[mt][nt] = __builtin_amdgcn_mfma_f32_16x16x32_bf16(
                            af[mt], bfr[nt], acc[mt][nt], 0, 0, 0);
            }
        }
    }

    const float rs = rsqrtf(1.f + 1e-5f);
    if (OUT_F32) {
        float* out = (float*)outv;
#pragma unroll
        for (int mt = 0; mt < 4; ++mt) {
#pragma unroll
            for (int reg = 0; reg < 4; ++reg) {
                int co = wm * 64 + mt * 16 + q * 4 + reg;
                float sc = g[co] * rs, bb = be[co];
#pragma unroll
                for (int nt = 0; nt < 4; ++nt) {
                    int l = l0 + wn * 64 + nt * 16 + lx;
                    out[((size_t)b * 128 + co) * LPIX + l] =
                        fmaxf(fmaf(acc[mt][nt][reg], sc, bb), 0.f);
                }
            }
        }
    } else {
        u16* out = (u16*)outv;
        for (int mh = 0; mh < 2; ++mh) {
            __syncthreads();
            if (wm == mh) {
#pragma unroll
                for (int mt = 0; mt < 4; ++mt)
#pragma unroll
                    for (int nt = 0; nt < 4; ++nt)
#pragma unroll
                        for (int reg = 0; reg < 4; ++reg)
                            sT[(wn * 64 + nt * 16 + lx) * 65 + mt * 16 + q * 4 + reg] =
                                acc[mt][nt][reg];
            }
            __syncthreads();
            for (int i = tid; i < 1024; i += 256) {
                int cog = i & 7, px = i >> 3;
                union { short8 v8; u16 u[8]; } pk;
#pragma unroll
                for (int j = 0; j < 8; ++j) {
                    int co = mh * 64 + cog * 8 + j;
                    pk.u[j] = f2bf(fmaxf(fmaf(sT[px * 65 + cog * 8 + j], g[co] * rs, be[co]), 0.f));
                }
                *(short8*)&out[((size_t)b * LPIX + l0 + px) * 128 + mh * 64 + cog * 8] = pk.v8;
            }
        }
    }
}

// ---------------------------------------------------------------------------
// 128->128 linear + bias via MFMA. in/out NHWC-flat bf16 [b*L][128].
// grid 1152 (64 px per block), block 256 (2x2 waves: M=64 x N=32).
// ---------------------------------------------------------------------------
__global__ __launch_bounds__(256) void linear_mfma(
    const u16* __restrict__ in, const u16* __restrict__ wp,
    const float* __restrict__ bias, u16* __restrict__ out)
{
    const int l0 = blockIdx.x * 64;
    const int tid = threadIdx.x, lane = tid & 63, wv = tid >> 6;
    const int wm = wv >> 1, wn = wv & 1;
    const int lx = lane & 15, q = lane >> 4;

    __shared__ char smem[4 * 64 * 40 * 2 + 4 * 128 * 40 * 2];   // 61,440 B
    u16* sX = (u16*)smem;                        // [c4][px 64][32 pitch 40]
    u16* sW = (u16*)(smem + 4 * 64 * 40 * 2);    // [c4][co 128][32 pitch 40]
    float* sT = (float*)smem;                    // epilogue [64][65]

    for (int i = tid; i < 1024; i += 256) {
        int k8 = i & 15, px = i >> 4;
        short8 v = *(const short8*)&in[((size_t)(l0 + px)) * 128 + k8 * 8];
        *(short8*)&sX[((k8 >> 2) * 64 + px) * 40 + (k8 & 3) * 8] = v;
    }
    for (int i = tid; i < 2048; i += 256) {
        int k8 = i & 15, co = i >> 4;
        short8 v = *(const short8*)&wp[(size_t)co * 128 + k8 * 8];
        *(short8*)&sW[((k8 >> 2) * 128 + co) * 40 + (k8 & 3) * 8] = v;
    }
    __syncthreads();

    f32x4 acc[4][2];
#pragma unroll
    for (int mt = 0; mt < 4; ++mt)
#pragma unroll
        for (int nt = 0; nt < 2; ++nt) acc[mt][nt] = (f32x4){0.f, 0.f, 0.f, 0.f};

#pragma unroll
    for (int c4 = 0; c4 < 4; ++c4) {
        short8 af[4], bfr[2];
#pragma unroll
        for (int mt = 0; mt < 4; ++mt)
            af[mt] = *(const short8*)&sW[(c4 * 128 + wm * 64 + mt * 16 + lx) * 40 + q * 8];
#pragma unroll
        for (int nt = 0; nt < 2; ++nt)
            bfr[nt] = *(const short8*)&sX[(c4 * 64 + wn * 32 + nt * 16 + lx) * 40 + q * 8];
#pragma unroll
        for (int mt = 0; mt < 4; ++mt)
#pragma unroll
            for (int nt = 0; nt < 2; ++nt)
                acc[mt][nt] = __builtin_amdgcn_mfma_f32_16x16x32_bf16(
                    af[mt], bfr[nt], acc[mt][nt], 0, 0, 0);
    }

    for (int mh = 0; mh < 2; ++mh) {
        __syncthreads();
        if (wm == mh) {
#pragma unroll
            for (int mt = 0; mt < 4; ++mt)
#pragma unroll
                for (int nt = 0; nt < 2; ++nt)
#pragma unroll
                    for (int reg = 0; reg < 4; ++reg)
                        sT[(wn * 32 + nt * 16 + lx) * 65 + mt * 16 + q * 4 + reg] =
                            acc[mt][nt][reg];
        }
        __syncthreads();
        for (int i = tid; i < 512; i += 256) {
            int cog = i & 7, px = i >> 3;
            union { short8 v8; u16 u[8]; } pk;
#pragma unroll
            for (int j = 0; j < 8; ++j) {
                int co = mh * 64 + cog * 8 + j;
                pk.u[j] = f2bf(sT[px * 65 + cog * 8 + j] + bias[co]);
            }
            *(short8*)&out[((size_t)(l0 + px)) * 128 + mh * 64 + cog * 8] = pk.v8;
        }
    }
}

// ---------------------------------------------------------------------------
// attn logits GEMM (MFMA) + bias + scale + softmax over q(9).
// grid (144 l-tiles of 64 px, 4 h, 8 b), block 256 (4 waves).
// ---------------------------------------------------------------------------
__global__ __launch_bounds__(256) void attn_mfma(
    const u16* __restrict__ fgb, const u16* __restrict__ awb,
    const float* __restrict__ ab, u16* __restrict__ A)
{
    const int lt = blockIdx.x, h = blockIdx.y, b = blockIdx.z;
    const int l0 = lt * 64;
    const int tid = threadIdx.x, lane = tid & 63, wv = tid >> 6;
    const int lx = lane & 15, q = lane >> 4;

    __shared__ char smem[4 * 64 * 40 * 2 + 4 * 96 * 40 * 2];   // 51,200 B
    u16* sX = (u16*)smem;                        // [c4][px 64][32 pitch 40]
    u16* sW = (u16*)(smem + 4 * 64 * 40 * 2);    // [c4][row 96][32 pitch 40]
    float* sL = (float*)smem;                    // epilogue logits [px 64][pitch 97]

    for (int i = tid; i < 1024; i += 256) {
        int k8 = i & 15, px = i >> 4;
        short8 v = *(const short8*)&fgb[((size_t)b * LPIX + l0 + px) * 128 + k8 * 8];
        *(short8*)&sX[((k8 >> 2) * 64 + px) * 40 + (k8 & 3) * 8] = v;
    }
    for (int i = tid; i < 1536; i += 256) {
        int k8 = i & 15, rr = i >> 4;           // rr 0..95, rows 81..95 zero-pad
        short8 v = {0, 0, 0, 0, 0, 0, 0, 0};
        if (rr < 81)
            v = *(const short8*)&awb[(size_t)(h * 81 + rr) * 128 + k8 * 8];
        *(short8*)&sW[((k8 >> 2) * 96 + rr) * 40 + (k8 & 3) * 8] = v;
    }
    __syncthreads();

    f32x4 acc[6];
#pragma unroll
    for (int j = 0; j < 6; ++j) acc[j] = (f32x4){0.f, 0.f, 0.f, 0.f};

#pragma unroll
    for (int c4 = 0; c4 < 4; ++c4) {
        short8 af = *(const short8*)&sX[(c4 * 64 + wv * 16 + lx) * 40 + q * 8];
#pragma unroll
        for (int j = 0; j < 6; ++j) {
            short8 bfr = *(const short8*)&sW[(c4 * 96 + j * 16 + lx) * 40 + q * 8];
            acc[j] = __builtin_amdgcn_mfma_f32_16x16x32_bf16(af, bfr, acc[j], 0, 0, 0);
        }
    }

    __syncthreads();   // done reading sX/sW; reuse as sL
#pragma unroll
    for (int j = 0; j < 6; ++j)
#pragma unroll
        for (int reg = 0; reg < 4; ++reg)
            sL[(wv * 16 + q * 4 + reg) * 97 + j * 16 + lx] = acc[j][reg];
    __syncthreads();

    for (int t = tid; t < 576; t += 256) {
        int px = t & 63, p = t >> 6;
        const int rbase = h * 81 + p * 9;
        float lg[9], m = -1e30f;
#pragma unroll
        for (int qq = 0; qq < 9; ++qq) {
            lg[qq] = (sL[px * 97 + p * 9 + qq] + ab[rbase + qq]) * kScale;
            m = fmaxf(m, lg[qq]);
        }
        float s = 0.f;
#pragma unroll
        for (int qq = 0; qq < 9; ++qq) { lg[qq] = __expf(lg[qq] - m); s += lg[qq]; }
        float inv = 1.f / s;
        u16* Ab = &A[(((size_t)(b * 4 + h) * 9 + p) * 9) * LPIX + l0 + px];
#pragma unroll
        for (int qq = 0; qq < 9; ++qq) Ab[(size_t)qq * LPIX] = f2bf(lg[qq] * inv);
    }
}

// ---------------------------------------------------------------------------
// fused einsum + fold (5x5 stencil collapse).
// Block 384 = one head x 4 full rows (384 px). Coalesced A reads (lane=px),
// v staged per-head in LDS (rows y0-2..y0+5 x 96 x 32ch bf16 = 49,152 B,
// 3 blocks/CU co-resident). Phase-2 LDS reads at 64B lane stride = 2-way
// bank aliasing (free). grid (24 y-tiles, 4 h, 8 b).
// ---------------------------------------------------------------------------
__global__ __launch_bounds__(384, 4) void attn_fold(
    const u16* __restrict__ A, const u16* __restrict__ v,
    u16* __restrict__ out)
{
    const int yt = blockIdx.x, h = blockIdx.y, b = blockIdx.z;
    const int y0 = yt * 4;
    const int tid = threadIdx.x;          // 0..383
    const int yl  = tid / 96;             // 0..3
    const int x   = tid - yl * 96;
    const int y   = y0 + yl;
    const int l   = y * 96 + x;

    __shared__ u16 sV[8 * 96 * 32];       // [r 8][xx 96][c 32] bf16 = 49,152 B

    // ---- stage v rows y0-2 .. y0+5 (this head's 32 ch) ----
    const u16* vb = v + (size_t)b * LPIX * 128 + h * 32;
    for (int t = tid; t < 3072; t += 384) {
        int k = t & 3, s = t >> 2;        // s = r*96+xx, k = uint4 within 64B
        int r = s / 96, xx = s - r * 96;
        int gy = y0 - 2 + r;
        uint4 uu = make_uint4(0u, 0u, 0u, 0u);
        if ((unsigned)gy < 96u)
            uu = *(const uint4*)&vb[(size_t)(gy * 96 + xx) * 128 + k * 8];
        *(uint4*)&sV[(size_t)s * 32 + k * 8] = uu;
    }

    // ---- stencil S[5][5] from 9 taps x 9 q of A (coalesced bf16 reads) ----
    float S[25];
#pragma unroll
    for (int i = 0; i < 25; ++i) S[i] = 0.f;

    const u16* Ab = A + ((size_t)(b * 4 + h) * 81) * (size_t)LPIX;
#pragma unroll
    for (int ki = 0; ki < 3; ++ki) {
        const int ly = y + 1 - ki;
        const bool vy = ((unsigned)ly < 96u);
#pragma unroll
        for (int kj = 0; kj < 3; ++kj) {
            const int lx2 = x + 1 - kj;
            if (vy && (unsigned)lx2 < 96u) {
                const u16* Ap = Ab + (size_t)(ki * 3 + kj) * 9 * (size_t)LPIX
                              + (ly * 96 + lx2);
#pragma unroll
                for (int qq = 0; qq < 9; ++qq) {
                    const int qi = qq / 3, qj = qq - qi * 3;
                    S[(qi - ki + 2) * 5 + (qj - kj + 2)] += bf2f(Ap[(size_t)qq * LPIX]);
                }
            }
        }
    }

    __syncthreads();   // staging complete before LDS reads

    // ---- 5x5 stencil over LDS v tile ----
    float acc[32];
#pragma unroll
    for (int c = 0; c < 32; ++c) acc[c] = 0.f;

#pragma unroll
    for (int oy = 0; oy < 5; ++oy) {
        const int r = yl + oy;            // LDS row: gy = y0-2+r = y+oy-2
#pragma unroll
        for (int ox = 0; ox < 5; ++ox) {
            const int xx = x + ox - 2;
            if ((unsigned)xx >= 96u) continue;
            const float sc = S[oy * 5 + ox];
            const u16* vp = &sV[(size_t)(r * 96 + xx) * 32];
#pragma unroll
            for (int c8 = 0; c8 < 4; ++c8) {
                const uint4 uu = *(const uint4*)&vp[c8 * 8];
                acc[c8 * 8 + 0] = fmaf(sc, __uint_as_float(uu.x << 16),          acc[c8 * 8 + 0]);
                acc[c8 * 8 + 1] = fmaf(sc, __uint_as_float(uu.x & 0xffff0000u), acc[c8 * 8 + 1]);
                acc[c8 * 8 + 2] = fmaf(sc, __uint_as_float(uu.y << 16),          acc[c8 * 8 + 2]);
                acc[c8 * 8 + 3] = fmaf(sc, __uint_as_float(uu.y & 0xffff0000u), acc[c8 * 8 + 3]);
                acc[c8 * 8 + 4] = fmaf(sc, __uint_as_float(uu.z << 16),          acc[c8 * 8 + 4]);
                acc[c8 * 8 + 5] = fmaf(sc, __uint_as_float(uu.z & 0xffff0000u), acc[c8 * 8 + 5]);
                acc[c8 * 8 + 6] = fmaf(sc, __uint_as_float(uu.w << 16),          acc[c8 * 8 + 6]);
                acc[c8 * 8 + 7] = fmaf(sc, __uint_as_float(uu.w & 0xffff0000u), acc[c8 * 8 + 7]);
            }
        }
    }

    u16* ob = &out[((size_t)b * LPIX + l) * 128 + h * 32];
#pragma unroll
    for (int gidx = 0; gidx < 4; ++gidx) {
        union { short8 v8; u16 u[8]; } pk;
#pragma unroll
        for (int j = 0; j < 8; ++j) pk.u[j] = f2bf(acc[gidx * 8 + j]);
        *(short8*)&ob[gidx * 8] = pk.v8;
    }
}

// ---------------------------------------------------------------------------
extern "C" void kernel_launch(void* const* d_in, const int* in_sizes, int n_in,
                              void* d_out, int out_size, void* d_ws, size_t ws_size,
                              hipStream_t stream)
{
    const float* x    = (const float*)d_in[0];
    const float* fg   = (const float*)d_in[1];
    const float* c1w  = (const float*)d_in[2];
    const float* bn1g = (const float*)d_in[3];
    const float* bn1b = (const float*)d_in[4];
    const float* c2w  = (const float*)d_in[5];
    const float* bn2g = (const float*)d_in[6];
    const float* bn2b = (const float*)d_in[7];
    const float* vw   = (const float*)d_in[8];
    const float* vb   = (const float*)d_in[9];
    const float* aw   = (const float*)d_in[10];
    const float* abv  = (const float*)d_in[11];
    const float* pw   = (const float*)d_in[12];
    const float* pb   = (const float*)d_in[13];
    const float* c3w  = (const float*)d_in[14];
    const float* bn3g = (const float*)d_in[15];
    const float* bn3b = (const float*)d_in[16];
    const float* c4w  = (const float*)d_in[17];
    const float* bn4g = (const float*)d_in[18];
    const float* bn4b = (const float*)d_in[19];

    char* wsp = (char*)d_ws;
    size_t off = 0;
    auto carve = [&](size_t bytes) {
        void* pp = wsp + off;
        off += (bytes + 255) & ~(size_t)255;
        return pp;
    };
    u16*   xb   = (u16*)carve((size_t)8 * LPIX * 64 * 2);     // x NHWC bf16
    u16*   fgb  = (u16*)carve((size_t)8 * LPIX * 128 * 2);    // fg NHWC bf16
    u16*   actA = (u16*)carve((size_t)8 * LPIX * 128 * 2);
    u16*   actB = (u16*)carve((size_t)8 * LPIX * 128 * 2);
    u16*   Abuf = (u16*)carve((size_t)8 * 324 * LPIX * 2);    // A bf16
    u16*   w1p  = (u16*)carve((size_t)9 * 2 * 128 * 32 * 2);
    u16*   w2p  = (u16*)carve((size_t)9 * 4 * 128 * 32 * 2);
    u16*   w3p  = (u16*)carve((size_t)9 * 4 * 128 * 32 * 2);
    u16*   w4p  = (u16*)carve((size_t)9 * 4 * 128 * 32 * 2);
    u16*   vwp  = (u16*)carve((size_t)128 * 128 * 2);
    u16*   pwp  = (u16*)carve((size_t)128 * 128 * 2);
    u16*   awb  = (u16*)carve((size_t)324 * 128 * 2);

    // --- pre-casts ---
    cast_nchw_nhwc<64><<<dim3(HW, 8), 256, 0, stream>>>(x, xb);
    cast_nchw_nhwc<128><<<dim3(HW, 8), 256, 0, stream>>>(fg, fgb);
    cast_conv_w<<<(9 * 64 * 128 + 255) / 256, 256, 0, stream>>>(c1w, w1p, 64);
    cast_conv_w<<<(9 * 128 * 128 + 255) / 256, 256, 0, stream>>>(c2w, w2p, 128);
    cast_conv_w<<<(9 * 128 * 128 + 255) / 256, 256, 0, stream>>>(c3w, w3p, 128);
    cast_conv_w<<<(9 * 128 * 128 + 255) / 256, 256, 0, stream>>>(c4w, w4p, 128);
    cast_mat<<<(16384 + 255) / 256, 256, 0, stream>>>(vw, vwp, 16384);
    cast_mat<<<(16384 + 255) / 256, 256, 0, stream>>>(pw, pwp, 16384);
    cast_mat<<<(324 * 128 + 255) / 256, 256, 0, stream>>>(aw, awb, 324 * 128);

    // --- pipeline ---
    conv_gemm<64, false><<<dim3(72, 8), 256, 0, stream>>>(xb, w1p, bn1g, bn1b, actA);
    conv_gemm<128, false><<<dim3(72, 8), 256, 0, stream>>>(actA, w2p, bn2g, bn2b, actB);
    linear_mfma<<<1152, 256, 0, stream>>>(actB, vwp, vb, actA);                 // v
    attn_mfma<<<dim3(144, 4, 8), 256, 0, stream>>>(fgb, awb, abv, Abuf);
    attn_fold<<<dim3(24, 4, 8), 384, 0, stream>>>(Abuf, actA, actB);            // folded
    linear_mfma<<<1152, 256, 0, stream>>>(actB, pwp, pb, actA);                 // p
    conv_gemm<128, false><<<dim3(72, 8), 256, 0, stream>>>(actA, w3p, bn3g, bn3b, actB);
    conv_gemm<128, true><<<dim3(72, 8), 256, 0, stream>>>(actB, w4p, bn4g, bn4b, d_out);
}

// Round 9
// 412.683 us; speedup vs baseline: 1.2521x; 1.1349x over previous
//
#include <hip/hip_runtime.h>
#include <math.h>

typedef __attribute__((ext_vector_type(8))) short short8;
typedef __attribute__((ext_vector_type(4))) float f32x4;
typedef unsigned short u16;
typedef unsigned int u32;

#define HW   96
#define LPIX 9216
static constexpr float kScale = 0.17677669529663687f;  // 1/sqrt(32)

__device__ inline u16 f2bf(float f) {
    u32 x = __float_as_uint(f);
    return (u16)((x + 0x7fffu + ((x >> 16) & 1u)) >> 16);   // RNE
}
__device__ inline float bf2f(u16 v) { return __uint_as_float((u32)v << 16); }

// ---------------------------------------------------------------------------
// NCHW fp32 -> NHWC bf16 transpose-cast. grid (96 y, 8 b), block 256.
// ---------------------------------------------------------------------------
template <int C>
__global__ __launch_bounds__(256) void cast_nchw_nhwc(
    const float* __restrict__ in, u16* __restrict__ out)
{
    const int y = blockIdx.x, b = blockIdx.y, tid = threadIdx.x;
    __shared__ float sT[HW * C];
    for (int i = tid; i < HW * C; i += 256) {
        int c = i / HW, xx = i - c * HW;
        sT[xx * C + c] = in[(((size_t)b * C + c) * HW + y) * HW + xx];
    }
    __syncthreads();
    for (int i = tid; i < HW * (C / 8); i += 256) {
        int c8 = i % (C / 8), xx = i / (C / 8);
        union { short8 v8; u16 u[8]; } pk;
#pragma unroll
        for (int j = 0; j < 8; ++j) pk.u[j] = f2bf(sT[xx * C + c8 * 8 + j]);
        *(short8*)&out[(((size_t)b * HW + y) * HW + xx) * C + c8 * 8] = pk.v8;
    }
}

// ---------------------------------------------------------------------------
// conv weights [co 128][ci CIN][3][3] fp32 -> [f 9][ci/32][co 128][32] bf16
// ---------------------------------------------------------------------------
__global__ void cast_conv_w(const float* __restrict__ w, u16* __restrict__ wp, int CIN)
{
    int n = 9 * CIN * 128;
    int i = blockIdx.x * 256 + threadIdx.x;
    if (i >= n) return;
    int cil = i & 31; int t = i >> 5; int co = t & 127; int t2 = t >> 7;
    int nc5 = CIN >> 5;
    int c5 = t2 % nc5; int f = t2 / nc5;
    int ci = c5 * 32 + cil;
    wp[i] = f2bf(w[(size_t)(co * CIN + ci) * 9 + f]);
}

// dense matrix fp32 -> bf16 (same layout)
__global__ void cast_mat(const float* __restrict__ in, u16* __restrict__ out, int n)
{
    int i = blockIdx.x * 256 + threadIdx.x;
    if (i < n) out[i] = f2bf(in[i]);
}

// ---------------------------------------------------------------------------
// conv3x3 + BN + ReLU, halo-tile implicit GEMM.
// Per 64-ci chunk: stage flat-pixel halo [324 px][64 ci] ONCE, then all
// 9 taps read shifted B fragments from the same LDS tile (predicated zero
// at image borders). Weights come straight from global (coalesced, L2-hot),
// so the tap loop has no barrier: 288 MFMAs between barriers (was 32).
// grid (72 px-blocks, 8 b), block 256 (2x2 waves, each M=64 x N=64).
// ---------------------------------------------------------------------------
template <int CIN, bool OUT_F32>
__global__ __launch_bounds__(256, 3) void conv_gemm(
    const u16* __restrict__ in, const u16* __restrict__ wp,
    const float* __restrict__ g, const float* __restrict__ be, void* outv)
{
    constexpr int NC6 = CIN / 64;       // 64-ci chunks
    constexpr int NC5 = CIN / 32;
    const int l0 = blockIdx.x * 128;
    const int b  = blockIdx.y;
    const int tid = threadIdx.x, lane = tid & 63, wv = tid >> 6;
    const int wm = wv >> 1, wn = wv & 1;
    const int lx = lane & 15, q = lane >> 4;

    __shared__ __align__(16) char smem[324 * 72 * 2];   // 46,656 B
    u16* sH = (u16*)smem;               // halo [hp 324][ci 64 pitch 72]
    float* sT = (float*)smem;           // epilogue [px 128][co 64 pitch 65] (33,280 B)

    // per-lane pixel coords for the 4 B-fragment pixels
    int py_[4], px_[4];
#pragma unroll
    for (int nt = 0; nt < 4; ++nt) {
        int l = l0 + wn * 64 + nt * 16 + lx;
        py_[nt] = l / 96; px_[nt] = l - py_[nt] * 96;
    }

    f32x4 acc[4][4];                    // [mt co][nt px]
#pragma unroll
    for (int mt = 0; mt < 4; ++mt)
#pragma unroll
        for (int nt = 0; nt < 4; ++nt) acc[mt][nt] = (f32x4){0.f, 0.f, 0.f, 0.f};

    for (int c6 = 0; c6 < NC6; ++c6) {
        __syncthreads();   // previous chunk's readers done
        // stage halo: flat pixels l0-97 .. l0+226, 64 ci -> 2592 short8
        for (int t = tid; t < 2592; t += 256) {
            int k = t & 7, hp = t >> 3;
            int lh = l0 - 97 + hp;
            short8 v = {0, 0, 0, 0, 0, 0, 0, 0};
            if (lh >= 0 && lh < LPIX)
                v = *(const short8*)&in[((size_t)b * LPIX + lh) * CIN + c6 * 64 + k * 8];
            *(short8*)&sH[hp * 72 + k * 8] = v;
        }
        __syncthreads();

#pragma unroll
        for (int f = 0; f < 9; ++f) {
            const int dy = f / 3 - 1, dx = f % 3 - 1;
            const int off = dy * 96 + dx + 97;       // in [0,194]
            bool ok[4];
#pragma unroll
            for (int nt = 0; nt < 4; ++nt) {
                int yy = py_[nt] + dy, xx = px_[nt] + dx;
                ok[nt] = ((unsigned)yy < 96u) & ((unsigned)xx < 96u);
            }
#pragma unroll
            for (int kk = 0; kk < 2; ++kk) {
                short8 af[4], bfr[4];
                // weights direct from global: 1024B/wave coalesced, L2-hot
#pragma unroll
                for (int mt = 0; mt < 4; ++mt)
                    af[mt] = *(const short8*)&wp[(size_t)(((f * NC5 + c6 * 2 + kk) * 128
                                                           + wm * 64 + mt * 16 + lx) * 32 + q * 8)];
#pragma unroll
                for (int nt = 0; nt < 4; ++nt) {
                    short8 t8 = *(const short8*)&sH[(wn * 64 + nt * 16 + lx + off) * 72
                                                    + kk * 32 + q * 8];
                    bfr[nt] = ok[nt] ? t8 : (short8){0, 0, 0, 0, 0, 0, 0, 0};
                }
#pragma unroll
                for (int mt = 0; mt < 4; ++mt)
#pragma unroll
                    for (int nt = 0; nt < 4; ++nt)
                        acc[mt][nt] = __builtin_amdgcn_mfma_f32_16x16x32_bf16(
                            af[mt], bfr[nt], acc[mt][nt], 0, 0, 0);
            }
        }
    }

    const float rs = rsqrtf(1.f + 1e-5f);
    if (OUT_F32) {
        float* out = (float*)outv;
#pragma unroll
        for (int mt = 0; mt < 4; ++mt) {
#pragma unroll
            for (int reg = 0; reg < 4; ++reg) {
                int co = wm * 64 + mt * 16 + q * 4 + reg;
                float sc = g[co] * rs, bb = be[co];
#pragma unroll
                for (int nt = 0; nt < 4; ++nt) {
                    int l = l0 + wn * 64 + nt * 16 + lx;
                    out[((size_t)b * 128 + co) * LPIX + l] =
                        fmaxf(fmaf(acc[mt][nt][reg], sc, bb), 0.f);
                }
            }
        }
    } else {
        u16* out = (u16*)outv;
        for (int mh = 0; mh < 2; ++mh) {
            __syncthreads();
            if (wm == mh) {
#pragma unroll
                for (int mt = 0; mt < 4; ++mt)
#pragma unroll
                    for (int nt = 0; nt < 4; ++nt)
#pragma unroll
                        for (int reg = 0; reg < 4; ++reg)
                            sT[(wn * 64 + nt * 16 + lx) * 65 + mt * 16 + q * 4 + reg] =
                                acc[mt][nt][reg];
            }
            __syncthreads();
            for (int i = tid; i < 1024; i += 256) {
                int cog = i & 7, px = i >> 3;
                union { short8 v8; u16 u[8]; } pk;
#pragma unroll
                for (int j = 0; j < 8; ++j) {
                    int co = mh * 64 + cog * 8 + j;
                    pk.u[j] = f2bf(fmaxf(fmaf(sT[px * 65 + cog * 8 + j], g[co] * rs, be[co]), 0.f));
                }
                *(short8*)&out[((size_t)b * LPIX + l0 + px) * 128 + mh * 64 + cog * 8] = pk.v8;
            }
        }
    }
}

// ---------------------------------------------------------------------------
// 128->128 linear + bias via MFMA. in/out NHWC-flat bf16 [b*L][128].
// grid 1152 (64 px per block), block 256 (2x2 waves: M=64 x N=32).
// ---------------------------------------------------------------------------
__global__ __launch_bounds__(256) void linear_mfma(
    const u16* __restrict__ in, const u16* __restrict__ wp,
    const float* __restrict__ bias, u16* __restrict__ out)
{
    const int l0 = blockIdx.x * 64;
    const int tid = threadIdx.x, lane = tid & 63, wv = tid >> 6;
    const int wm = wv >> 1, wn = wv & 1;
    const int lx = lane & 15, q = lane >> 4;

    __shared__ char smem[4 * 64 * 40 * 2 + 4 * 128 * 40 * 2];   // 61,440 B
    u16* sX = (u16*)smem;                        // [c4][px 64][32 pitch 40]
    u16* sW = (u16*)(smem + 4 * 64 * 40 * 2);    // [c4][co 128][32 pitch 40]
    float* sT = (float*)smem;                    // epilogue [64][65]

    for (int i = tid; i < 1024; i += 256) {
        int k8 = i & 15, px = i >> 4;
        short8 v = *(const short8*)&in[((size_t)(l0 + px)) * 128 + k8 * 8];
        *(short8*)&sX[((k8 >> 2) * 64 + px) * 40 + (k8 & 3) * 8] = v;
    }
    for (int i = tid; i < 2048; i += 256) {
        int k8 = i & 15, co = i >> 4;
        short8 v = *(const short8*)&wp[(size_t)co * 128 + k8 * 8];
        *(short8*)&sW[((k8 >> 2) * 128 + co) * 40 + (k8 & 3) * 8] = v;
    }
    __syncthreads();

    f32x4 acc[4][2];
#pragma unroll
    for (int mt = 0; mt < 4; ++mt)
#pragma unroll
        for (int nt = 0; nt < 2; ++nt) acc[mt][nt] = (f32x4){0.f, 0.f, 0.f, 0.f};

#pragma unroll
    for (int c4 = 0; c4 < 4; ++c4) {
        short8 af[4], bfr[2];
#pragma unroll
        for (int mt = 0; mt < 4; ++mt)
            af[mt] = *(const short8*)&sW[(c4 * 128 + wm * 64 + mt * 16 + lx) * 40 + q * 8];
#pragma unroll
        for (int nt = 0; nt < 2; ++nt)
            bfr[nt] = *(const short8*)&sX[(c4 * 64 + wn * 32 + nt * 16 + lx) * 40 + q * 8];
#pragma unroll
        for (int mt = 0; mt < 4; ++mt)
#pragma unroll
            for (int nt = 0; nt < 2; ++nt)
                acc[mt][nt] = __builtin_amdgcn_mfma_f32_16x16x32_bf16(
                    af[mt], bfr[nt], acc[mt][nt], 0, 0, 0);
    }

    for (int mh = 0; mh < 2; ++mh) {
        __syncthreads();
        if (wm == mh) {
#pragma unroll
            for (int mt = 0; mt < 4; ++mt)
#pragma unroll
                for (int nt = 0; nt < 2; ++nt)
#pragma unroll
                    for (int reg = 0; reg < 4; ++reg)
                        sT[(wn * 32 + nt * 16 + lx) * 65 + mt * 16 + q * 4 + reg] =
                            acc[mt][nt][reg];
        }
        __syncthreads();
        for (int i = tid; i < 512; i += 256) {
            int cog = i & 7, px = i >> 3;
            union { short8 v8; u16 u[8]; } pk;
#pragma unroll
            for (int j = 0; j < 8; ++j) {
                int co = mh * 64 + cog * 8 + j;
                pk.u[j] = f2bf(sT[px * 65 + cog * 8 + j] + bias[co]);
            }
            *(short8*)&out[((size_t)(l0 + px)) * 128 + mh * 64 + cog * 8] = pk.v8;
        }
    }
}

// ---------------------------------------------------------------------------
// attn logits GEMM (MFMA) + bias + scale + softmax over q(9).
// grid (144 l-tiles of 64 px, 4 h, 8 b), block 256 (4 waves).
// ---------------------------------------------------------------------------
__global__ __launch_bounds__(256) void attn_mfma(
    const u16* __restrict__ fgb, const u16* __restrict__ awb,
    const float* __restrict__ ab, u16* __restrict__ A)
{
    const int lt = blockIdx.x, h = blockIdx.y, b = blockIdx.z;
    const int l0 = lt * 64;
    const int tid = threadIdx.x, lane = tid & 63, wv = tid >> 6;
    const int lx = lane & 15, q = lane >> 4;

    __shared__ char smem[4 * 64 * 40 * 2 + 4 * 96 * 40 * 2];   // 51,200 B
    u16* sX = (u16*)smem;                        // [c4][px 64][32 pitch 40]
    u16* sW = (u16*)(smem + 4 * 64 * 40 * 2);    // [c4][row 96][32 pitch 40]
    float* sL = (float*)smem;                    // epilogue logits [px 64][pitch 97]

    for (int i = tid; i < 1024; i += 256) {
        int k8 = i & 15, px = i >> 4;
        short8 v = *(const short8*)&fgb[((size_t)b * LPIX + l0 + px) * 128 + k8 * 8];
        *(short8*)&sX[((k8 >> 2) * 64 + px) * 40 + (k8 & 3) * 8] = v;
    }
    for (int i = tid; i < 1536; i += 256) {
        int k8 = i & 15, rr = i >> 4;           // rr 0..95, rows 81..95 zero-pad
        short8 v = {0, 0, 0, 0, 0, 0, 0, 0};
        if (rr < 81)
            v = *(const short8*)&awb[(size_t)(h * 81 + rr) * 128 + k8 * 8];
        *(short8*)&sW[((k8 >> 2) * 96 + rr) * 40 + (k8 & 3) * 8] = v;
    }
    __syncthreads();

    f32x4 acc[6];
#pragma unroll
    for (int j = 0; j < 6; ++j) acc[j] = (f32x4){0.f, 0.f, 0.f, 0.f};

#pragma unroll
    for (int c4 = 0; c4 < 4; ++c4) {
        short8 af = *(const short8*)&sX[(c4 * 64 + wv * 16 + lx) * 40 + q * 8];
#pragma unroll
        for (int j = 0; j < 6; ++j) {
            short8 bfr = *(const short8*)&sW[(c4 * 96 + j * 16 + lx) * 40 + q * 8];
            acc[j] = __builtin_amdgcn_mfma_f32_16x16x32_bf16(af, bfr, acc[j], 0, 0, 0);
        }
    }

    __syncthreads();   // done reading sX/sW; reuse as sL
#pragma unroll
    for (int j = 0; j < 6; ++j)
#pragma unroll
        for (int reg = 0; reg < 4; ++reg)
            sL[(wv * 16 + q * 4 + reg) * 97 + j * 16 + lx] = acc[j][reg];
    __syncthreads();

    for (int t = tid; t < 576; t += 256) {
        int px = t & 63, p = t >> 6;
        const int rbase = h * 81 + p * 9;
        float lg[9], m = -1e30f;
#pragma unroll
        for (int qq = 0; qq < 9; ++qq) {
            lg[qq] = (sL[px * 97 + p * 9 + qq] + ab[rbase + qq]) * kScale;
            m = fmaxf(m, lg[qq]);
        }
        float s = 0.f;
#pragma unroll
        for (int qq = 0; qq < 9; ++qq) { lg[qq] = __expf(lg[qq] - m); s += lg[qq]; }
        float inv = 1.f / s;
        u16* Ab = &A[(((size_t)(b * 4 + h) * 9 + p) * 9) * LPIX + l0 + px];
#pragma unroll
        for (int qq = 0; qq < 9; ++qq) Ab[(size_t)qq * LPIX] = f2bf(lg[qq] * inv);
    }
}

// ---------------------------------------------------------------------------
// fused einsum + fold (5x5 stencil collapse).
// Block 384 = one head x 4 full rows (384 px). Coalesced A reads (lane=px),
// v staged per-head in LDS (rows y0-2..y0+5 x 96 x 32ch bf16 = 49,152 B).
// grid (24 y-tiles, 4 h, 8 b).
// ---------------------------------------------------------------------------
__global__ __launch_bounds__(384, 4) void attn_fold(
    const u16* __restrict__ A, const u16* __restrict__ v,
    u16* __restrict__ out)
{
    const int yt = blockIdx.x, h = blockIdx.y, b = blockIdx.z;
    const int y0 = yt * 4;
    const int tid = threadIdx.x;          // 0..383
    const int yl  = tid / 96;             // 0..3
    const int x   = tid - yl * 96;
    const int y   = y0 + yl;
    const int l   = y * 96 + x;

    __shared__ u16 sV[8 * 96 * 32];       // [r 8][xx 96][c 32] bf16 = 49,152 B

    // ---- stage v rows y0-2 .. y0+5 (this head's 32 ch) ----
    const u16* vb = v + (size_t)b * LPIX * 128 + h * 32;
    for (int t = tid; t < 3072; t += 384) {
        int k = t & 3, s = t >> 2;        // s = r*96+xx, k = uint4 within 64B
        int r = s / 96, xx = s - r * 96;
        int gy = y0 - 2 + r;
        uint4 uu = make_uint4(0u, 0u, 0u, 0u);
        if ((unsigned)gy < 96u)
            uu = *(const uint4*)&vb[(size_t)(gy * 96 + xx) * 128 + k * 8];
        *(uint4*)&sV[(size_t)s * 32 + k * 8] = uu;
    }

    // ---- stencil S[5][5] from 9 taps x 9 q of A (coalesced bf16 reads) ----
    float S[25];
#pragma unroll
    for (int i = 0; i < 25; ++i) S[i] = 0.f;

    const u16* Ab = A + ((size_t)(b * 4 + h) * 81) * (size_t)LPIX;
#pragma unroll
    for (int ki = 0; ki < 3; ++ki) {
        const int ly = y + 1 - ki;
        const bool vy = ((unsigned)ly < 96u);
#pragma unroll
        for (int kj = 0; kj < 3; ++kj) {
            const int lx2 = x + 1 - kj;
            if (vy && (unsigned)lx2 < 96u) {
                const u16* Ap = Ab + (size_t)(ki * 3 + kj) * 9 * (size_t)LPIX
                              + (ly * 96 + lx2);
#pragma unroll
                for (int qq = 0; qq < 9; ++qq) {
                    const int qi = qq / 3, qj = qq - qi * 3;
                    S[(qi - ki + 2) * 5 + (qj - kj + 2)] += bf2f(Ap[(size_t)qq * LPIX]);
                }
            }
        }
    }

    __syncthreads();   // staging complete before LDS reads

    // ---- 5x5 stencil over LDS v tile ----
    float acc[32];
#pragma unroll
    for (int c = 0; c < 32; ++c) acc[c] = 0.f;

#pragma unroll
    for (int oy = 0; oy < 5; ++oy) {
        const int r = yl + oy;            // LDS row: gy = y0-2+r = y+oy-2
#pragma unroll
        for (int ox = 0; ox < 5; ++ox) {
            const int xx = x + ox - 2;
            if ((unsigned)xx >= 96u) continue;
            const float sc = S[oy * 5 + ox];
            const u16* vp = &sV[(size_t)(r * 96 + xx) * 32];
#pragma unroll
            for (int c8 = 0; c8 < 4; ++c8) {
                const uint4 uu = *(const uint4*)&vp[c8 * 8];
                acc[c8 * 8 + 0] = fmaf(sc, __uint_as_float(uu.x << 16),          acc[c8 * 8 + 0]);
                acc[c8 * 8 + 1] = fmaf(sc, __uint_as_float(uu.x & 0xffff0000u), acc[c8 * 8 + 1]);
                acc[c8 * 8 + 2] = fmaf(sc, __uint_as_float(uu.y << 16),          acc[c8 * 8 + 2]);
                acc[c8 * 8 + 3] = fmaf(sc, __uint_as_float(uu.y & 0xffff0000u), acc[c8 * 8 + 3]);
                acc[c8 * 8 + 4] = fmaf(sc, __uint_as_float(uu.z << 16),          acc[c8 * 8 + 4]);
                acc[c8 * 8 + 5] = fmaf(sc, __uint_as_float(uu.z & 0xffff0000u), acc[c8 * 8 + 5]);
                acc[c8 * 8 + 6] = fmaf(sc, __uint_as_float(uu.w << 16),          acc[c8 * 8 + 6]);
                acc[c8 * 8 + 7] = fmaf(sc, __uint_as_float(uu.w & 0xffff0000u), acc[c8 * 8 + 7]);
            }
        }
    }

    u16* ob = &out[((size_t)b * LPIX + l) * 128 + h * 32];
#pragma unroll
    for (int gidx = 0; gidx < 4; ++gidx) {
        union { short8 v8; u16 u[8]; } pk;
#pragma unroll
        for (int j = 0; j < 8; ++j) pk.u[j] = f2bf(acc[gidx * 8 + j]);
        *(short8*)&ob[gidx * 8] = pk.v8;
    }
}

// ---------------------------------------------------------------------------
extern "C" void kernel_launch(void* const* d_in, const int* in_sizes, int n_in,
                              void* d_out, int out_size, void* d_ws, size_t ws_size,
                              hipStream_t stream)
{
    const float* x    = (const float*)d_in[0];
    const float* fg   = (const float*)d_in[1];
    const float* c1w  = (const float*)d_in[2];
    const float* bn1g = (const float*)d_in[3];
    const float* bn1b = (const float*)d_in[4];
    const float* c2w  = (const float*)d_in[5];
    const float* bn2g = (const float*)d_in[6];
    const float* bn2b = (const float*)d_in[7];
    const float* vw   = (const float*)d_in[8];
    const float* vb   = (const float*)d_in[9];
    const float* aw   = (const float*)d_in[10];
    const float* abv  = (const float*)d_in[11];
    const float* pw   = (const float*)d_in[12];
    const float* pb   = (const float*)d_in[13];
    const float* c3w  = (const float*)d_in[14];
    const float* bn3g = (const float*)d_in[15];
    const float* bn3b = (const float*)d_in[16];
    const float* c4w  = (const float*)d_in[17];
    const float* bn4g = (const float*)d_in[18];
    const float* bn4b = (const float*)d_in[19];

    char* wsp = (char*)d_ws;
    size_t off = 0;
    auto carve = [&](size_t bytes) {
        void* pp = wsp + off;
        off += (bytes + 255) & ~(size_t)255;
        return pp;
    };
    u16*   xb   = (u16*)carve((size_t)8 * LPIX * 64 * 2);     // x NHWC bf16
    u16*   fgb  = (u16*)carve((size_t)8 * LPIX * 128 * 2);    // fg NHWC bf16
    u16*   actA = (u16*)carve((size_t)8 * LPIX * 128 * 2);
    u16*   actB = (u16*)carve((size_t)8 * LPIX * 128 * 2);
    u16*   Abuf = (u16*)carve((size_t)8 * 324 * LPIX * 2);    // A bf16
    u16*   w1p  = (u16*)carve((size_t)9 * 2 * 128 * 32 * 2);
    u16*   w2p  = (u16*)carve((size_t)9 * 4 * 128 * 32 * 2);
    u16*   w3p  = (u16*)carve((size_t)9 * 4 * 128 * 32 * 2);
    u16*   w4p  = (u16*)carve((size_t)9 * 4 * 128 * 32 * 2);
    u16*   vwp  = (u16*)carve((size_t)128 * 128 * 2);
    u16*   pwp  = (u16*)carve((size_t)128 * 128 * 2);
    u16*   awb  = (u16*)carve((size_t)324 * 128 * 2);

    // --- pre-casts ---
    cast_nchw_nhwc<64><<<dim3(HW, 8), 256, 0, stream>>>(x, xb);
    cast_nchw_nhwc<128><<<dim3(HW, 8), 256, 0, stream>>>(fg, fgb);
    cast_conv_w<<<(9 * 64 * 128 + 255) / 256, 256, 0, stream>>>(c1w, w1p, 64);
    cast_conv_w<<<(9 * 128 * 128 + 255) / 256, 256, 0, stream>>>(c2w, w2p, 128);
    cast_conv_w<<<(9 * 128 * 128 + 255) / 256, 256, 0, stream>>>(c3w, w3p, 128);
    cast_conv_w<<<(9 * 128 * 128 + 255) / 256, 256, 0, stream>>>(c4w, w4p, 128);
    cast_mat<<<(16384 + 255) / 256, 256, 0, stream>>>(vw, vwp, 16384);
    cast_mat<<<(16384 + 255) / 256, 256, 0, stream>>>(pw, pwp, 16384);
    cast_mat<<<(324 * 128 + 255) / 256, 256, 0, stream>>>(aw, awb, 324 * 128);

    // --- pipeline ---
    conv_gemm<64, false><<<dim3(72, 8), 256, 0, stream>>>(xb, w1p, bn1g, bn1b, actA);
    conv_gemm<128, false><<<dim3(72, 8), 256, 0, stream>>>(actA, w2p, bn2g, bn2b, actB);
    linear_mfma<<<1152, 256, 0, stream>>>(actB, vwp, vb, actA);                 // v
    attn_mfma<<<dim3(144, 4, 8), 256, 0, stream>>>(fgb, awb, abv, Abuf);
    attn_fold<<<dim3(24, 4, 8), 384, 0, stream>>>(Abuf, actA, actB);            // folded
    linear_mfma<<<1152, 256, 0, stream>>>(actB, pwp, pb, actA);                 // p
    conv_gemm<128, false><<<dim3(72, 8), 256, 0, stream>>>(actA, w3p, bn3g, bn3b, actB);
    conv_gemm<128, true><<<dim3(72, 8), 256, 0, stream>>>(actB, w4p, bn4g, bn4b, d_out);
}